// Round 6
// baseline (331.432 us; speedup 1.0000x reference)
//
#include <hip/hip_runtime.h>

// out[j] = sum(x) for all j — single persistent kernel, one-way flag sync.
// Phase 1: grid-stride float4 partial sums -> partials[] in ws; RELEASE
//          atomicAdd on a counter.
// Wait:    all threads poll counter with ACQUIRE loads + s_sleep backoff
//          (all 2048 blocks are co-resident: 8 blocks/CU x 256 CUs).
// Phase 2: each block re-reduces the 2048 partials in a fixed deterministic
//          tree (bit-identical everywhere), then fills its slice of out.
// Counter is zeroed per launch via hipMemsetAsync (ws is poisoned 0xAA).

#define NBLK 2048
#define NTHR 256

typedef float vfloat4 __attribute__((ext_vector_type(4)));

__global__ __launch_bounds__(NTHR, 8) void fused_spin_kernel(
    const vfloat4* __restrict__ x4, const float* __restrict__ x,
    float* __restrict__ partials, unsigned int* __restrict__ counter,
    vfloat4* __restrict__ out4, float* __restrict__ out,
    int n4, int n)
{
    __shared__ float smem[NTHR / 64];
    __shared__ float total_sh;

    int tid    = blockIdx.x * blockDim.x + threadIdx.x;
    int stride = gridDim.x * blockDim.x;
    int lane   = threadIdx.x & 63;
    int wid    = threadIdx.x >> 6;

    // ---- Phase 1: per-block partial sum ----
    float s = 0.0f;
    for (int i = tid; i < n4; i += stride) {
        vfloat4 v = x4[i];
        s += (v.x + v.y) + (v.z + v.w);
    }
    int tail_start = n4 * 4;
    int tail_n = n - tail_start;
    if (tid < tail_n) s += x[tail_start + tid];

    #pragma unroll
    for (int off = 32; off > 0; off >>= 1)
        s += __shfl_down(s, off, 64);

    if (lane == 0) smem[wid] = s;
    __syncthreads();
    if (threadIdx.x == 0) {
        float t = 0.0f;
        #pragma unroll
        for (int w = 0; w < NTHR / 64; ++w) t += smem[w];
        partials[blockIdx.x] = t;
        __hip_atomic_fetch_add(counter, 1u, __ATOMIC_RELEASE,
                               __HIP_MEMORY_SCOPE_AGENT);
    }
    __syncthreads();  // protect smem reuse below

    // ---- One-way wait: all blocks' partials published ----
    while (__hip_atomic_load(counter, __ATOMIC_ACQUIRE,
                             __HIP_MEMORY_SCOPE_AGENT) < NBLK)
        __builtin_amdgcn_s_sleep(8);

    // ---- Phase 2: every block re-reduces the NBLK partials ----
    const vfloat4* p4 = (const vfloat4*)partials;
    float r = 0.0f;
    #pragma unroll
    for (int k = 0; k < NBLK / 4 / NTHR; ++k) {
        vfloat4 v = p4[threadIdx.x + k * NTHR];
        r += (v.x + v.y) + (v.z + v.w);
    }
    #pragma unroll
    for (int off = 32; off > 0; off >>= 1)
        r += __shfl_down(r, off, 64);

    if (lane == 0) smem[wid] = r;
    __syncthreads();
    if (threadIdx.x == 0) {
        float t = 0.0f;
        #pragma unroll
        for (int w = 0; w < NTHR / 64; ++w) t += smem[w];
        total_sh = t;
    }
    __syncthreads();

    float t = total_sh;
    vfloat4 v = { t, t, t, t };

    for (int i = tid; i < n4; i += stride)
        out4[i] = v;
    if (tid < tail_n) out[tail_start + tid] = t;
}

extern "C" void kernel_launch(void* const* d_in, const int* in_sizes, int n_in,
                              void* d_out, int out_size, void* d_ws, size_t ws_size,
                              hipStream_t stream)
{
    const float*   x    = (const float*)d_in[0];
    const vfloat4* x4   = (const vfloat4*)d_in[0];
    float*         out  = (float*)d_out;
    vfloat4*       out4 = (vfloat4*)d_out;

    int n  = in_sizes[0];
    int n4 = n / 4;

    float*        partials = (float*)d_ws;                       // 8 KB
    unsigned int* counter  = (unsigned int*)((char*)d_ws + 8192); // 4 B

    hipMemsetAsync(counter, 0, sizeof(unsigned int), stream);
    fused_spin_kernel<<<NBLK, NTHR, 0, stream>>>(
        x4, x, partials, counter, out4, out, n4, out_size);
}

// Round 7
// 51.367 us; speedup vs baseline: 6.4522x; 6.4522x over previous
//
#include <hip/hip_runtime.h>

// out[j] = sum(x) for all j.
// Kernel 1: per-block partial sums, grid-stride float4, unroll-by-4 with
//           4 independent accumulators (4 outstanding 16B loads/thread).
// Kernel 2: each block re-reduces the 2048 partials (fixed deterministic
//           tree, L2/L3-resident, 8 KB) then broadcast-fills its slice
//           of out with plain 16B stores.

#define NBLK 2048
#define NTHR 256

typedef float vfloat4 __attribute__((ext_vector_type(4)));

__global__ __launch_bounds__(NTHR) void reduce_partial_kernel(
    const vfloat4* __restrict__ x4, const float* __restrict__ x,
    float* __restrict__ partials, int n4, int n)
{
    int tid    = blockIdx.x * blockDim.x + threadIdx.x;
    int stride = gridDim.x * blockDim.x;

    float s0 = 0.0f, s1 = 0.0f, s2 = 0.0f, s3 = 0.0f;
    int i = tid;
    for (; i + 3 * stride < n4; i += 4 * stride) {
        vfloat4 v0 = x4[i];
        vfloat4 v1 = x4[i + stride];
        vfloat4 v2 = x4[i + 2 * stride];
        vfloat4 v3 = x4[i + 3 * stride];
        s0 += (v0.x + v0.y) + (v0.z + v0.w);
        s1 += (v1.x + v1.y) + (v1.z + v1.w);
        s2 += (v2.x + v2.y) + (v2.z + v2.w);
        s3 += (v3.x + v3.y) + (v3.z + v3.w);
    }
    for (; i < n4; i += stride) {
        vfloat4 v = x4[i];
        s0 += (v.x + v.y) + (v.z + v.w);
    }
    float s = (s0 + s1) + (s2 + s3);

    // scalar tail (n not divisible by 4)
    int tail_start = n4 * 4;
    int tail_n = n - tail_start;
    if (tid < tail_n) s += x[tail_start + tid];

    #pragma unroll
    for (int off = 32; off > 0; off >>= 1)
        s += __shfl_down(s, off, 64);

    __shared__ float smem[NTHR / 64];
    int lane = threadIdx.x & 63;
    int wid  = threadIdx.x >> 6;
    if (lane == 0) smem[wid] = s;
    __syncthreads();
    if (threadIdx.x == 0) {
        float t = 0.0f;
        #pragma unroll
        for (int w = 0; w < NTHR / 64; ++w) t += smem[w];
        partials[blockIdx.x] = t;
    }
}

__global__ __launch_bounds__(NTHR) void fill_total_kernel(
    vfloat4* __restrict__ out4, float* __restrict__ out,
    const float* __restrict__ partials, int n4, int n)
{
    // Per-block re-reduction of the NBLK partials (identical fixed tree in
    // every block -> bit-identical total everywhere). 8 KB, L2-resident.
    const vfloat4* p4 = (const vfloat4*)partials;
    float r = 0.0f;
    #pragma unroll
    for (int k = 0; k < NBLK / 4 / NTHR; ++k) {
        vfloat4 v = p4[threadIdx.x + k * NTHR];
        r += (v.x + v.y) + (v.z + v.w);
    }
    #pragma unroll
    for (int off = 32; off > 0; off >>= 1)
        r += __shfl_down(r, off, 64);

    __shared__ float smem[NTHR / 64];
    __shared__ float total_sh;
    int lane = threadIdx.x & 63;
    int wid  = threadIdx.x >> 6;
    if (lane == 0) smem[wid] = r;
    __syncthreads();
    if (threadIdx.x == 0) {
        float t = 0.0f;
        #pragma unroll
        for (int w = 0; w < NTHR / 64; ++w) t += smem[w];
        total_sh = t;
    }
    __syncthreads();

    float t = total_sh;
    vfloat4 v = { t, t, t, t };

    int tid    = blockIdx.x * blockDim.x + threadIdx.x;
    int stride = gridDim.x * blockDim.x;
    for (int i = tid; i < n4; i += stride)
        out4[i] = v;

    int tail_start = n4 * 4;
    int tail_n = n - tail_start;
    if (tid < tail_n) out[tail_start + tid] = t;
}

extern "C" void kernel_launch(void* const* d_in, const int* in_sizes, int n_in,
                              void* d_out, int out_size, void* d_ws, size_t ws_size,
                              hipStream_t stream)
{
    const float*   x    = (const float*)d_in[0];
    const vfloat4* x4   = (const vfloat4*)d_in[0];
    float*         out  = (float*)d_out;
    vfloat4*       out4 = (vfloat4*)d_out;

    int n  = in_sizes[0];
    int n4 = n / 4;

    float* partials = (float*)d_ws;  // NBLK floats

    reduce_partial_kernel<<<NBLK, NTHR, 0, stream>>>(x4, x, partials, n4, n);
    fill_total_kernel<<<NBLK, NTHR, 0, stream>>>(out4, out, partials, n4, out_size);
}

// Round 8
// 50.490 us; speedup vs baseline: 6.5643x; 1.0174x over previous
//
#include <hip/hip_runtime.h>

// out[j] = sum(x) for all j.
// Kernel 1: per-block partial sums (float4 vectorized, grid-stride) -> ws.
// Kernel 2: each block re-reduces the 2048 partials (fixed deterministic
//           tree, L2/L3-resident, ~8 KB) then broadcast-fills its slice
//           of out with plain 16B stores.
//
// Measured best structure (50.0 us). Rejected by measurement:
//  - 3-kernel pipeline (53.4): tiny middle dispatch is pure latency.
//  - NT stores (57.0): degrades the write stream vs plain stores.
//  - cooperative grid.sync (155): device-wide barrier pathological on 8 XCDs.
//  - spin-flag persistent kernel (331): agent-scope polling thrashes L2s.
//  - unroll-by-4 reduce (51.4): already BW-bound, no MLP gain.

#define NBLK 2048
#define NTHR 256

typedef float vfloat4 __attribute__((ext_vector_type(4)));

__global__ __launch_bounds__(NTHR) void reduce_partial_kernel(
    const vfloat4* __restrict__ x4, const float* __restrict__ x,
    float* __restrict__ partials, int n4, int n)
{
    int tid    = blockIdx.x * blockDim.x + threadIdx.x;
    int stride = gridDim.x * blockDim.x;

    float s = 0.0f;
    for (int i = tid; i < n4; i += stride) {
        vfloat4 v = x4[i];
        s += (v.x + v.y) + (v.z + v.w);
    }
    // scalar tail (n not divisible by 4)
    int tail_start = n4 * 4;
    int tail_n = n - tail_start;
    if (tid < tail_n) s += x[tail_start + tid];

    #pragma unroll
    for (int off = 32; off > 0; off >>= 1)
        s += __shfl_down(s, off, 64);

    __shared__ float smem[NTHR / 64];
    int lane = threadIdx.x & 63;
    int wid  = threadIdx.x >> 6;
    if (lane == 0) smem[wid] = s;
    __syncthreads();
    if (threadIdx.x == 0) {
        float t = 0.0f;
        #pragma unroll
        for (int w = 0; w < NTHR / 64; ++w) t += smem[w];
        partials[blockIdx.x] = t;
    }
}

__global__ __launch_bounds__(NTHR) void fill_total_kernel(
    vfloat4* __restrict__ out4, float* __restrict__ out,
    const float* __restrict__ partials, int n4, int n)
{
    // Per-block re-reduction of the NBLK partials (identical fixed tree in
    // every block -> bit-identical total everywhere). 8 KB, L2/L3-resident.
    const vfloat4* p4 = (const vfloat4*)partials;
    float r = 0.0f;
    #pragma unroll
    for (int k = 0; k < NBLK / 4 / NTHR; ++k) {
        vfloat4 v = p4[threadIdx.x + k * NTHR];
        r += (v.x + v.y) + (v.z + v.w);
    }
    #pragma unroll
    for (int off = 32; off > 0; off >>= 1)
        r += __shfl_down(r, off, 64);

    __shared__ float smem[NTHR / 64];
    __shared__ float total_sh;
    int lane = threadIdx.x & 63;
    int wid  = threadIdx.x >> 6;
    if (lane == 0) smem[wid] = r;
    __syncthreads();
    if (threadIdx.x == 0) {
        float t = 0.0f;
        #pragma unroll
        for (int w = 0; w < NTHR / 64; ++w) t += smem[w];
        total_sh = t;
    }
    __syncthreads();

    float t = total_sh;
    vfloat4 v = { t, t, t, t };

    int tid    = blockIdx.x * blockDim.x + threadIdx.x;
    int stride = gridDim.x * blockDim.x;
    for (int i = tid; i < n4; i += stride)
        out4[i] = v;

    int tail_start = n4 * 4;
    int tail_n = n - tail_start;
    if (tid < tail_n) out[tail_start + tid] = t;
}

extern "C" void kernel_launch(void* const* d_in, const int* in_sizes, int n_in,
                              void* d_out, int out_size, void* d_ws, size_t ws_size,
                              hipStream_t stream)
{
    const float*   x    = (const float*)d_in[0];
    const vfloat4* x4   = (const vfloat4*)d_in[0];
    float*         out  = (float*)d_out;
    vfloat4*       out4 = (vfloat4*)d_out;

    int n  = in_sizes[0];
    int n4 = n / 4;

    float* partials = (float*)d_ws;  // NBLK floats

    reduce_partial_kernel<<<NBLK, NTHR, 0, stream>>>(x4, x, partials, n4, n);
    fill_total_kernel<<<NBLK, NTHR, 0, stream>>>(out4, out, partials, n4, out_size);
}